// Round 10
// baseline (1468.382 us; speedup 1.0000x reference)
//
#include <hip/hip_runtime.h>
#include <cstdint>
#include <cstddef>

typedef short  short8  __attribute__((ext_vector_type(8)));
typedef float  float4v __attribute__((ext_vector_type(4)));
typedef int    int4v   __attribute__((ext_vector_type(4)));

#define MFMA_B16(a,b,c) __builtin_amdgcn_mfma_f32_16x16x32_bf16(a,b,c,0,0,0)

static constexpr int B_  = 512;
static constexpr int T_  = 256;
static constexpr int DIN = 32;
static constexpr int H_  = 128;
static constexpr int TGT = 64;

// ---- workspace layout (bytes) ----
static constexpr size_t OFF_XFRAG = 0;                          // 8,388,608
static constexpr size_t OFF_EW0   = 8388608;                    // 163,840
static constexpr size_t OFF_EW1LO = OFF_EW0   + 163840;         // 131,072 (kb 0..3)
static constexpr size_t OFF_EW1HI = OFF_EW1LO + 131072;         // 131,072 (kb 4..7)
static constexpr size_t OFF_DW0   = OFF_EW1HI + 131072;         // 163,840
static constexpr size_t OFF_DW1LO = OFF_DW0   + 163840;         // 131,072
static constexpr size_t OFF_DW1HI = OFF_DW1LO + 131072;         // 131,072
static constexpr size_t OFF_LIN   = OFF_DW1HI + 131072;         // 8,192
static constexpr size_t OFF_BIAS  = OFF_LIN   + 8192;           // 8,320
static constexpr size_t WS_NEED   = OFF_BIAS  + 8320;           // ~9.26 MB

__device__ __forceinline__ short f2bf(float f){
  unsigned u = __float_as_uint(f);
  unsigned r = (u + 0x7fffu + ((u>>16)&1u)) >> 16;   // RNE
  return (short)(r & 0xffffu);
}
__device__ __forceinline__ float fast_sigm(float x){
  float e = __expf(-x);
  return __builtin_amdgcn_rcpf(1.f + e);
}
// sigm(a)*tanh(b) with a single shared rcp (saves 2 quarter-rate ops/cell)
__device__ __forceinline__ float sig_tanh(float a, float b){
  float ea = __expf(-a);
  float eb = __expf(-2.f*b);
  float d  = __builtin_amdgcn_rcpf((1.f+ea)*(1.f+eb));
  return (1.f-eb)*d;
}

// ---- inline-asm MFMA with B operand pinned to AGPRs ----
// First-of-chain variant pads 2 wait states for the VALU(bias init) -> SrcC hazard.
__device__ __forceinline__ void mfma_a_first(float4v& acc, short8 a, int4v b){
  asm volatile("s_nop 1\n\tv_mfma_f32_16x16x32_bf16 %0, %1, %2, %0"
               : "+v"(acc) : "v"(a), "a"(b));
}
__device__ __forceinline__ void mfma_a(float4v& acc, short8 a, int4v b){
  asm volatile("v_mfma_f32_16x16x32_bf16 %0, %1, %2, %0"
               : "+v"(acc) : "v"(a), "a"(b));
}
// MFMA-D -> VALU-read fence for all 8 accumulators (ordered after all volatile MFMAs)
__device__ __forceinline__ void mfma_fence8(float4v& x0, float4v& x1, float4v& x2, float4v& x3,
                                            float4v& x4, float4v& x5, float4v& x6, float4v& x7){
  asm volatile("s_nop 7\n\ts_nop 7"
    : "+v"(x0),"+v"(x1),"+v"(x2),"+v"(x3),"+v"(x4),"+v"(x5),"+v"(x6),"+v"(x7));
}

// ---------------- prep: x -> bf16 A-fragment tiles ----------------
__global__ void prep_x_kernel(const float* __restrict__ x, short8* __restrict__ xfrag){
  int i = blockIdx.x*256 + threadIdx.x;           // 32*256*64 entries
  if (i >= 32*256*64) return;
  int l    = i & 63;
  int t    = (i >> 6) & 255;
  int bblk = i >> 14;
  int b    = bblk*16 + (l & 15);
  const float* src = x + ((size_t)(b*T_ + t))*DIN + ((l>>4)*8);
  short8 v;
  #pragma unroll
  for (int j=0;j<8;j++) v[j] = f2bf(src[j]);
  xfrag[i] = v;
}

// ---------------- prep: weights -> bf16 B-fragment tiles ----------------
__device__ __forceinline__ void pack160(short8* __restrict__ dst,
                                        const float* __restrict__ Wih,   // (512,32)
                                        const float* __restrict__ Whh,   // (512,128)
                                        int e){
  int nt = e/320; int r = e%320; int kb = r/64; int l = r%64;
  int n  = nt*16 + (l&15);
  short8 v;
  #pragma unroll
  for (int j=0;j<8;j++){
    int k = kb*32 + (l>>4)*8 + j;
    float f = (k < 32) ? Wih[n*32 + k] : Whh[n*128 + (k-32)];
    v[j] = f2bf(f);
  }
  dst[e] = v;
}
// split variant: kb 0..3 -> lo array, kb 4..7 -> hi array
__device__ __forceinline__ void pack256s(short8* __restrict__ dlo, short8* __restrict__ dhi,
                                         const float* __restrict__ Wih,   // (512,128)
                                         const float* __restrict__ Whh,   // (512,128)
                                         int e){
  int nt = e/512; int r = e%512; int kb = r/64; int l = r%64;
  int n  = nt*16 + (l&15);
  short8 v;
  #pragma unroll
  for (int j=0;j<8;j++){
    int k = kb*32 + (l>>4)*8 + j;
    float f = (k < 128) ? Wih[n*128 + k] : Whh[n*128 + (k-128)];
    v[j] = f2bf(f);
  }
  if (kb < 4) dlo[(nt*4 + kb)*64 + l]     = v;
  else        dhi[(nt*4 + (kb-4))*64 + l] = v;
}

__global__ void prep_w_kernel(
    const float* __restrict__ eWih0, const float* __restrict__ eWhh0,
    const float* __restrict__ eWih1, const float* __restrict__ eWhh1,
    const float* __restrict__ dWih0, const float* __restrict__ dWhh0,
    const float* __restrict__ dWih1, const float* __restrict__ dWhh1,
    const float* __restrict__ linW,
    const float* __restrict__ eb0a, const float* __restrict__ eb0b,
    const float* __restrict__ eb1a, const float* __restrict__ eb1b,
    const float* __restrict__ db0a, const float* __restrict__ db0b,
    const float* __restrict__ db1a, const float* __restrict__ db1b,
    const float* __restrict__ linb,
    short8* __restrict__ encW0,
    short8* __restrict__ encW1lo, short8* __restrict__ encW1hi,
    short8* __restrict__ decW0,
    short8* __restrict__ decW1lo, short8* __restrict__ decW1hi,
    short8* __restrict__ linT,  float* __restrict__ biases)
{
  int i = blockIdx.x*256 + threadIdx.x;
  if (i < 10240)       { pack160(encW0, eWih0, eWhh0, i); }
  else if (i < 26624)  { pack256s(encW1lo, encW1hi, eWih1, eWhh1, i-10240); }
  else if (i < 36864)  { pack160(decW0, dWih0, dWhh0, i-26624); }
  else if (i < 53248)  { pack256s(decW1lo, decW1hi, dWih1, dWhh1, i-36864); }
  else if (i < 53760)  {
    int e = i - 53248;                       // lin: 2nt * 4kb * 64
    int nt = e/256; int r = e%256; int kb = r/64; int l = r%64;
    int n = nt*16 + (l&15);
    short8 v;
    #pragma unroll
    for (int j=0;j<8;j++){
      int k = kb*32 + (l>>4)*8 + j;          // k < 128
      v[j] = f2bf(linW[n*128 + k]);
    }
    linT[e] = v;
  }
  else if (i < 55840)  {
    int e = i - 53760;                       // 2080 bias entries
    float v;
    if      (e < 512)  v = eb0a[e]       + eb0b[e];
    else if (e < 1024) v = eb1a[e-512]   + eb1b[e-512];
    else if (e < 1536) v = db0a[e-1024]  + db0b[e-1024];
    else if (e < 2048) v = db1a[e-1536]  + db1b[e-1536];
    else               v = linb[e-2048];
    biases[e] = v;
  }
}

// ---------------- main fused persistent kernel ----------------
// 32 blocks (16 batch rows each) x 256 threads (4 waves, 1 wave/SIMD).
// Per-SIMD unified RF = 512 regs (measured via R4/R7/R8): at 1 wave/SIMD a
// wave gets 256 arch VGPR + 256 AGPR. W1 (256 regs) is FORCED into AGPRs by
// inline-asm MFMAs with "a"-constrained B operands (the builtin path never
// allocates AGPRs for B — R8 evidence). W0 h-part (128) in arch VGPRs;
// W0 x-part + lin in LDS. Hazards at asm boundaries handled manually:
// s_nop 1 before first MFMA of each chain (VALU->SrcC), s_nop 7 x2 fence
// before activations (MFMA D->VALU read).
__global__ __launch_bounds__(256, 1) void lstm_main_kernel(
    const short8* __restrict__ xfrag,
    const short8* __restrict__ encW0,
    const short8* __restrict__ encW1lo, const short8* __restrict__ encW1hi,
    const short8* __restrict__ decW0,
    const short8* __restrict__ decW1lo, const short8* __restrict__ decW1hi,
    const short8* __restrict__ linT,  const float* __restrict__ biases,
    float* __restrict__ out)
{
  __shared__ __align__(16) short8 Wx[2048];       // W0 x-part, 32 KB
  __shared__ __align__(16) short Abuf[16][520];   // h state, parity double-buffered
  __shared__ __align__(16) short inpA[16][40];    // decoder input frame
  __shared__ __align__(16) short8 Wlin[512];      // projection weights

  const int tid  = threadIdx.x;
  const int w    = tid >> 6;
  const int l    = tid & 63;
  const int col  = l & 15;
  const int lq   = l >> 4;
  const int bblk = blockIdx.x;

  // stage W0 x-part into LDS + zero h state
  for (int i = tid; i < 2048; i += 256) Wx[i] = encW0[(size_t)(i>>6)*320 + (i&63)];
  for (int i = tid; i < 16*520; i += 256) ((short*)Abuf)[i] = 0;

  const int wxbase = 2*w*64 + l;   // + (j>>1)*512 + (j&1)*64 per tile

  // ---- persistent weight registers (encoder first) ----
  short8 W0h[8][4];   // L0 h-part: tile j, kb 1..4  (arch VGPRs)
  int4v  W1r[8][8];   // L1 full:   tile j, kb 0..7  (AGPRs via asm "a")
  float  bs0[8], bs1[8];
  #pragma unroll
  for (int j=0;j<8;j++){
    int nt = 8*(j>>1) + 2*w + (j&1);
    #pragma unroll
    for (int kb=0;kb<4;kb++) W0h[j][kb] = encW0[(size_t)nt*320 + (size_t)(kb+1)*64 + l];
    #pragma unroll
    for (int kb=0;kb<4;kb++) W1r[j][kb]   = ((const int4v*)encW1lo)[(size_t)nt*256 + (size_t)kb*64 + l];
    #pragma unroll
    for (int kb=0;kb<4;kb++) W1r[j][kb+4] = ((const int4v*)encW1hi)[(size_t)nt*256 + (size_t)kb*64 + l];
    bs0[j] = biases[      nt*16 + col];
    bs1[j] = biases[512 + nt*16 + col];
  }

  float c0[8] = {0,0,0,0,0,0,0,0};
  float c1[8] = {0,0,0,0,0,0,0,0};

  const short8* xf = xfrag + (size_t)bblk*T_*64 + l;
  short8 a0 = xf[0];
  __syncthreads();

  // ---- peel: i=0, L0 only (h0(-1)=0 -> only x term + bias) ----
  {
    float4v acc0[8];
    #pragma unroll
    for (int j=0;j<8;j++){
      float4v a = {bs0[j],bs0[j],bs0[j],bs0[j]};
      acc0[j] = MFMA_B16(a0, Wx[wxbase + (j>>1)*512 + (j&1)*64], a);
    }
    a0 = xf[64];
    #pragma unroll
    for (int p=0;p<2;p++)
      #pragma unroll
      for (int q=0;q<4;q++){
        float cc = sig_tanh(acc0[p][q], acc0[4+p][q]);   // f*c0 = 0
        c0[p*4+q] = cc;
        Abuf[lq*4+q][0 + (2*w+p)*16 + col] = f2bf(sig_tanh(acc0[6+p][q], cc));
      }
    __syncthreads();
  }

  // ---- main: i = 1..255 : L0(i) + L1(i-1) ----
  #pragma unroll 2
  for (int i = 1; i < T_; i++){
    const int p_h0_r = ((i-1)&1)*128;          // h0(i-1) — shared by L0 and L1
    const int p_h0_w = (i&1)*128;              // h0(i)
    const int p_h1_r = 256 + (i&1)*128;        // h1(i-2)
    const int p_h1_w = 256 + ((i-1)&1)*128;    // h1(i-1)

    short8 hp[4];
    #pragma unroll
    for (int kb=0;kb<4;kb++) hp[kb]  = *(const short8*)&Abuf[col][p_h0_r + kb*32 + lq*8];

    // ---- L0 MFMAs (builtin, VGPR weights) ----
    float4v acc0[8];
    #pragma unroll
    for (int j=0;j<8;j++){
      float4v a = {bs0[j],bs0[j],bs0[j],bs0[j]};
      a = MFMA_B16(a0, Wx[wxbase + (j>>1)*512 + (j&1)*64], a);
      #pragma unroll
      for (int kb=0;kb<4;kb++) a = MFMA_B16(hp[kb], W0h[j][kb], a);
      acc0[j] = a;
    }
    a0 = xf[(size_t)((i+1 < T_) ? i+1 : i)*64];   // prefetch next frame
    // ---- act0 ----
    #pragma unroll
    for (int p=0;p<2;p++)
      #pragma unroll
      for (int q=0;q<4;q++){
        float cc = fast_sigm(acc0[2+p][q])*c0[p*4+q]
                 + sig_tanh(acc0[p][q], acc0[4+p][q]);
        c0[p*4+q] = cc;
        Abuf[lq*4+q][p_h0_w + (2*w+p)*16 + col] = f2bf(sig_tanh(acc0[6+p][q], cc));
      }

    // ---- L1 MFMAs (asm, AGPR weights) ----
    short8 h1p[4];
    #pragma unroll
    for (int kb=0;kb<4;kb++) h1p[kb] = *(const short8*)&Abuf[col][p_h1_r + kb*32 + lq*8];
    float4v acc1[8];
    #pragma unroll
    for (int j=0;j<8;j++){
      float4v a = {bs1[j],bs1[j],bs1[j],bs1[j]};
      mfma_a_first(a, hp[0], W1r[j][0]);
      #pragma unroll
      for (int kb=1;kb<4;kb++) mfma_a(a, hp[kb],  W1r[j][kb]);
      #pragma unroll
      for (int kb=0;kb<4;kb++) mfma_a(a, h1p[kb], W1r[j][kb+4]);
      acc1[j] = a;
    }
    mfma_fence8(acc1[0],acc1[1],acc1[2],acc1[3],acc1[4],acc1[5],acc1[6],acc1[7]);
    // ---- act1 ----
    #pragma unroll
    for (int p=0;p<2;p++)
      #pragma unroll
      for (int q=0;q<4;q++){
        float cc = fast_sigm(acc1[2+p][q])*c1[p*4+q]
                 + sig_tanh(acc1[p][q], acc1[4+p][q]);
        c1[p*4+q] = cc;
        Abuf[lq*4+q][p_h1_w + (2*w+p)*16 + col] = f2bf(sig_tanh(acc1[6+p][q], cc));
      }
    __syncthreads();
  }

  // ---- epilogue: L1 for t = 255 ----
  {
    const int p_h0_r = 128;        // h0(255), parity 1
    const int p_h1_r = 256 + 0;    // h1(254), parity 0
    const int p_h1_w = 256 + 128;  // h1(255), parity 1
    short8 hp[4], h1p[4];
    #pragma unroll
    for (int kb=0;kb<4;kb++) hp[kb]  = *(const short8*)&Abuf[col][p_h0_r + kb*32 + lq*8];
    #pragma unroll
    for (int kb=0;kb<4;kb++) h1p[kb] = *(const short8*)&Abuf[col][p_h1_r + kb*32 + lq*8];
    float4v acc1[8];
    #pragma unroll
    for (int j=0;j<8;j++){
      float4v a = {bs1[j],bs1[j],bs1[j],bs1[j]};
      mfma_a_first(a, hp[0], W1r[j][0]);
      #pragma unroll
      for (int kb=1;kb<4;kb++) mfma_a(a, hp[kb],  W1r[j][kb]);
      #pragma unroll
      for (int kb=0;kb<4;kb++) mfma_a(a, h1p[kb], W1r[j][kb+4]);
      acc1[j] = a;
    }
    mfma_fence8(acc1[0],acc1[1],acc1[2],acc1[3],acc1[4],acc1[5],acc1[6],acc1[7]);
    #pragma unroll
    for (int p=0;p<2;p++)
      #pragma unroll
      for (int q=0;q<4;q++){
        float cc = fast_sigm(acc1[2+p][q])*c1[p*4+q]
                 + sig_tanh(acc1[p][q], acc1[4+p][q]);
        c1[p*4+q] = cc;
        Abuf[lq*4+q][p_h1_w + (2*w+p)*16 + col] = f2bf(sig_tanh(acc1[6+p][q], cc));
      }
    __syncthreads();
  }

  // ---- swap weights to decoder ----
  for (int i = tid; i < 2048; i += 256) Wx[i] = decW0[(size_t)(i>>6)*320 + (i&63)];
  for (int i = tid; i < 512;  i += 256) Wlin[i] = linT[i];
  #pragma unroll
  for (int j=0;j<8;j++){
    int nt = 8*(j>>1) + 2*w + (j&1);
    #pragma unroll
    for (int kb=0;kb<4;kb++) W0h[j][kb] = decW0[(size_t)nt*320 + (size_t)(kb+1)*64 + l];
    #pragma unroll
    for (int kb=0;kb<4;kb++) W1r[j][kb]   = ((const int4v*)decW1lo)[(size_t)nt*256 + (size_t)kb*64 + l];
    #pragma unroll
    for (int kb=0;kb<4;kb++) W1r[j][kb+4] = ((const int4v*)decW1hi)[(size_t)nt*256 + (size_t)kb*64 + l];
    bs0[j] = biases[1024 + nt*16 + col];
    bs1[j] = biases[1536 + nt*16 + col];
  }
  float blin = (w < 2) ? biases[2048 + w*16 + col] : 0.f;
  if (w == 0){
    *(short8*)&inpA[col][lq*8] = xf[(size_t)(T_-1)*64];   // dec input 0 = x[:,-1,:]
  }
  __syncthreads();

  // ---------------- decoder: 64 steps, 3 phases ----------------
  // enc left h0/h1 at parity 1 -> dec td reads parity (td+1)&1, writes td&1.
  #pragma unroll 2
  for (int td = 0; td < TGT; td++){
    const int h0r = ((td+1)&1) * 128;
    const int h0w = 128 - h0r;
    const int h1r = 256 + h0r;
    const int h1w = 256 + h0w;

    // ---- phase 1: layer 0 ----
    short8 a0d = *(const short8*)&inpA[col][lq*8];
    short8 hp[4];
    #pragma unroll
    for (int kb=0;kb<4;kb++) hp[kb] = *(const short8*)&Abuf[col][h0r + kb*32 + lq*8];
    float4v acc0[8];
    #pragma unroll
    for (int j=0;j<8;j++){
      float4v a = {bs0[j],bs0[j],bs0[j],bs0[j]};
      a = MFMA_B16(a0d, Wx[wxbase + (j>>1)*512 + (j&1)*64], a);
      #pragma unroll
      for (int kb=0;kb<4;kb++) a = MFMA_B16(hp[kb], W0h[j][kb], a);
      acc0[j] = a;
    }
    #pragma unroll
    for (int p=0;p<2;p++)
      #pragma unroll
      for (int q=0;q<4;q++){
        float cc = fast_sigm(acc0[2+p][q])*c0[p*4+q]
                 + sig_tanh(acc0[p][q], acc0[4+p][q]);
        c0[p*4+q] = cc;
        Abuf[lq*4+q][h0w + (2*w+p)*16 + col] = f2bf(sig_tanh(acc0[6+p][q], cc));
      }
    __syncthreads();

    // ---- phase 2: layer 1 (asm, AGPR weights) ----
    short8 a1lo[4], a1hi[4];
    #pragma unroll
    for (int kb=0;kb<4;kb++) a1lo[kb] = *(const short8*)&Abuf[col][h0w + kb*32 + lq*8];
    #pragma unroll
    for (int kb=0;kb<4;kb++) a1hi[kb] = *(const short8*)&Abuf[col][h1r + kb*32 + lq*8];
    float4v acc1[8];
    #pragma unroll
    for (int j=0;j<8;j++){
      float4v a = {bs1[j],bs1[j],bs1[j],bs1[j]};
      mfma_a_first(a, a1lo[0], W1r[j][0]);
      #pragma unroll
      for (int kb=1;kb<4;kb++) mfma_a(a, a1lo[kb], W1r[j][kb]);
      #pragma unroll
      for (int kb=0;kb<4;kb++) mfma_a(a, a1hi[kb], W1r[j][kb+4]);
      acc1[j] = a;
    }
    mfma_fence8(acc1[0],acc1[1],acc1[2],acc1[3],acc1[4],acc1[5],acc1[6],acc1[7]);
    #pragma unroll
    for (int p=0;p<2;p++)
      #pragma unroll
      for (int q=0;q<4;q++){
        float cc = fast_sigm(acc1[2+p][q])*c1[p*4+q]
                 + sig_tanh(acc1[p][q], acc1[4+p][q]);
        c1[p*4+q] = cc;
        Abuf[lq*4+q][h1w + (2*w+p)*16 + col] = f2bf(sig_tanh(acc1[6+p][q], cc));
      }
    __syncthreads();

    // ---- phase 3: projection + feedback ----
    if (w < 2){
      short8 hf[4];
      #pragma unroll
      for (int kb=0;kb<4;kb++) hf[kb] = *(const short8*)&Abuf[col][h1w + kb*32 + lq*8];
      float4v a = {blin,blin,blin,blin};
      #pragma unroll
      for (int kb=0;kb<4;kb++) a = MFMA_B16(hf[kb], Wlin[(w*4+kb)*64 + l], a);
      #pragma unroll
      for (int q=0;q<4;q++){
        float v = a[q];
        int b = bblk*16 + lq*4 + q;
        out[((size_t)b*TGT + td)*DIN + (w*16 + col)] = v;
        inpA[lq*4+q][w*16 + col] = f2bf(v);
      }
    }
    __syncthreads();
  }
}

// ---------------- host ----------------
extern "C" void kernel_launch(void* const* d_in, const int* in_sizes, int n_in,
                              void* d_out, int out_size, void* d_ws, size_t ws_size,
                              hipStream_t stream) {
  const float* x      = (const float*)d_in[0];
  const float* eWih0  = (const float*)d_in[2];
  const float* eWhh0  = (const float*)d_in[3];
  const float* eb0a   = (const float*)d_in[4];
  const float* eb0b   = (const float*)d_in[5];
  const float* eWih1  = (const float*)d_in[6];
  const float* eWhh1  = (const float*)d_in[7];
  const float* eb1a   = (const float*)d_in[8];
  const float* eb1b   = (const float*)d_in[9];
  const float* dWih0  = (const float*)d_in[10];
  const float* dWhh0  = (const float*)d_in[11];
  const float* db0a   = (const float*)d_in[12];
  const float* db0b   = (const float*)d_in[13];
  const float* dWih1  = (const float*)d_in[14];
  const float* dWhh1  = (const float*)d_in[15];
  const float* db1a   = (const float*)d_in[16];
  const float* db1b   = (const float*)d_in[17];
  const float* linW   = (const float*)d_in[18];
  const float* linb   = (const float*)d_in[19];

  char* ws = (char*)d_ws;
  short8* xfrag   = (short8*)(ws + OFF_XFRAG);
  short8* encW0   = (short8*)(ws + OFF_EW0);
  short8* encW1lo = (short8*)(ws + OFF_EW1LO);
  short8* encW1hi = (short8*)(ws + OFF_EW1HI);
  short8* decW0   = (short8*)(ws + OFF_DW0);
  short8* decW1lo = (short8*)(ws + OFF_DW1LO);
  short8* decW1hi = (short8*)(ws + OFF_DW1HI);
  short8* linT    = (short8*)(ws + OFF_LIN);
  float*  biases  = (float*)(ws + OFF_BIAS);

  prep_x_kernel<<<2048, 256, 0, stream>>>(x, xfrag);
  prep_w_kernel<<<219, 256, 0, stream>>>(
      eWih0,eWhh0,eWih1,eWhh1,dWih0,dWhh0,dWih1,dWhh1,linW,
      eb0a,eb0b,eb1a,eb1b,db0a,db0b,db1a,db1b,linb,
      encW0,encW1lo,encW1hi,decW0,decW1lo,decW1hi,linT,biases);
  lstm_main_kernel<<<32, 256, 0, stream>>>(
      xfrag, encW0, encW1lo, encW1hi, decW0, decW1lo, decW1hi,
      linT, biases, (float*)d_out);
}

// Round 11
// 683.217 us; speedup vs baseline: 2.1492x; 2.1492x over previous
//
#include <hip/hip_runtime.h>
#include <cstdint>
#include <cstddef>

typedef short  short8  __attribute__((ext_vector_type(8)));
typedef float  float4v __attribute__((ext_vector_type(4)));

#define MFMA_B16(a,b,c) __builtin_amdgcn_mfma_f32_16x16x32_bf16(a,b,c,0,0,0)

static constexpr int B_  = 512;
static constexpr int T_  = 256;
static constexpr int DIN = 32;
static constexpr int H_  = 128;
static constexpr int TGT = 64;

static constexpr float L2E  = 1.4426950408889634f;   // log2(e)
static constexpr float L2E2 = 2.8853900817779268f;   // 2*log2(e)

// ---- workspace layout (bytes) ----
static constexpr size_t OFF_XFRAG = 0;                          // 8,388,608
static constexpr size_t OFF_EW0   = 8388608;                    // 163,840
static constexpr size_t OFF_EW1LO = OFF_EW0   + 163840;         // 131,072 (kb 0..3)
static constexpr size_t OFF_EW1HI = OFF_EW1LO + 131072;         // 131,072 (kb 4..7)
static constexpr size_t OFF_DW0   = OFF_EW1HI + 131072;         // 163,840
static constexpr size_t OFF_DW1LO = OFF_DW0   + 163840;         // 131,072
static constexpr size_t OFF_DW1HI = OFF_DW1LO + 131072;         // 131,072
static constexpr size_t OFF_LIN   = OFF_DW1HI + 131072;         // 8,192
static constexpr size_t OFF_BIAS  = OFF_LIN   + 8192;           // 8,320
static constexpr size_t WS_NEED   = OFF_BIAS  + 8320;           // ~9.26 MB

// ---- dynamic LDS layout (bytes) ----
static constexpr int SM_W    = 0;          // short8 Wlds[8192]   = 131,072 (W1 hi-half)
static constexpr int SM_ABUF = 131072;     // short Abuf[16][520] = 16,640
static constexpr int SM_INP  = 147712;     // short inpA[16][40]  = 1,280
static constexpr int SM_LIN  = 148992;     // short8 Wlin[512]    = 8,192
static constexpr int SM_TOTAL= 157184;     // <= 163,840

__device__ __forceinline__ short f2bf(float f){
  unsigned u = __float_as_uint(f);
  unsigned r = (u + 0x7fffu + ((u>>16)&1u)) >> 16;   // RNE
  return (short)(r & 0xffffu);
}
// gate pre-activations arrive pre-scaled by log2e (i,f,o) / 2*log2e (g):
__device__ __forceinline__ float sigm2(float x){           // sigmoid, folded
  return __builtin_amdgcn_rcpf(1.f + __builtin_amdgcn_exp2f(-x));
}
__device__ __forceinline__ float st2(float a, float b){    // sigm(a)*tanh(b), both folded
  float ea = __builtin_amdgcn_exp2f(-a);
  float eb = __builtin_amdgcn_exp2f(-b);
  float d  = __builtin_amdgcn_rcpf((1.f+ea)*(1.f+eb));
  return (1.f-eb)*d;
}
__device__ __forceinline__ float st2c(float a, float c){   // sigm(a folded)*tanh(c raw)
  float ea = __builtin_amdgcn_exp2f(-a);
  float eb = __builtin_amdgcn_exp2f(-L2E2*c);
  float d  = __builtin_amdgcn_rcpf((1.f+ea)*(1.f+eb));
  return (1.f-eb)*d;
}
__device__ __forceinline__ float gate_scale(int n){        // n = gate row 0..511
  return ((n >> 7) == 2) ? L2E2 : L2E;                     // g-gate rows get 2*log2e
}

// ---------------- prep: x -> bf16 A-fragment tiles ----------------
__global__ void prep_x_kernel(const float* __restrict__ x, short8* __restrict__ xfrag){
  int i = blockIdx.x*256 + threadIdx.x;           // 32*256*64 entries
  if (i >= 32*256*64) return;
  int l    = i & 63;
  int t    = (i >> 6) & 255;
  int bblk = i >> 14;
  int b    = bblk*16 + (l & 15);
  const float* src = x + ((size_t)(b*T_ + t))*DIN + ((l>>4)*8);
  short8 v;
  #pragma unroll
  for (int j=0;j<8;j++) v[j] = f2bf(src[j]);
  xfrag[i] = v;
}

// ---------------- prep: weights -> bf16 B-fragment tiles (log2e-folded) ----------------
__device__ __forceinline__ void pack160(short8* __restrict__ dst,
                                        const float* __restrict__ Wih,   // (512,32)
                                        const float* __restrict__ Whh,   // (512,128)
                                        int e){
  int nt = e/320; int r = e%320; int kb = r/64; int l = r%64;
  int n  = nt*16 + (l&15);
  float s = gate_scale(n);
  short8 v;
  #pragma unroll
  for (int j=0;j<8;j++){
    int k = kb*32 + (l>>4)*8 + j;
    float f = (k < 32) ? Wih[n*32 + k] : Whh[n*128 + (k-32)];
    v[j] = f2bf(f*s);
  }
  dst[e] = v;
}
// split variant: kb 0..3 -> lo array, kb 4..7 -> hi array
__device__ __forceinline__ void pack256s(short8* __restrict__ dlo, short8* __restrict__ dhi,
                                         const float* __restrict__ Wih,   // (512,128)
                                         const float* __restrict__ Whh,   // (512,128)
                                         int e){
  int nt = e/512; int r = e%512; int kb = r/64; int l = r%64;
  int n  = nt*16 + (l&15);
  float s = gate_scale(n);
  short8 v;
  #pragma unroll
  for (int j=0;j<8;j++){
    int k = kb*32 + (l>>4)*8 + j;
    float f = (k < 128) ? Wih[n*128 + k] : Whh[n*128 + (k-128)];
    v[j] = f2bf(f*s);
  }
  if (kb < 4) dlo[(nt*4 + kb)*64 + l]     = v;
  else        dhi[(nt*4 + (kb-4))*64 + l] = v;
}

__global__ void prep_w_kernel(
    const float* __restrict__ eWih0, const float* __restrict__ eWhh0,
    const float* __restrict__ eWih1, const float* __restrict__ eWhh1,
    const float* __restrict__ dWih0, const float* __restrict__ dWhh0,
    const float* __restrict__ dWih1, const float* __restrict__ dWhh1,
    const float* __restrict__ linW,
    const float* __restrict__ eb0a, const float* __restrict__ eb0b,
    const float* __restrict__ eb1a, const float* __restrict__ eb1b,
    const float* __restrict__ db0a, const float* __restrict__ db0b,
    const float* __restrict__ db1a, const float* __restrict__ db1b,
    const float* __restrict__ linb,
    short8* __restrict__ encW0,
    short8* __restrict__ encW1lo, short8* __restrict__ encW1hi,
    short8* __restrict__ decW0,
    short8* __restrict__ decW1lo, short8* __restrict__ decW1hi,
    short8* __restrict__ linT,  float* __restrict__ biases)
{
  int i = blockIdx.x*256 + threadIdx.x;
  if (i < 10240)       { pack160(encW0, eWih0, eWhh0, i); }
  else if (i < 26624)  { pack256s(encW1lo, encW1hi, eWih1, eWhh1, i-10240); }
  else if (i < 36864)  { pack160(decW0, dWih0, dWhh0, i-26624); }
  else if (i < 53248)  { pack256s(decW1lo, decW1hi, dWih1, dWhh1, i-36864); }
  else if (i < 53760)  {
    int e = i - 53248;                       // lin: 2nt * 4kb * 64 (NOT scaled)
    int nt = e/256; int r = e%256; int kb = r/64; int l = r%64;
    int n = nt*16 + (l&15);
    short8 v;
    #pragma unroll
    for (int j=0;j<8;j++){
      int k = kb*32 + (l>>4)*8 + j;          // k < 128
      v[j] = f2bf(linW[n*128 + k]);
    }
    linT[e] = v;
  }
  else if (i < 55840)  {
    int e = i - 53760;                       // 2080 bias entries
    float v;
    if      (e < 512)  v = (eb0a[e]       + eb0b[e]      ) * gate_scale(e);
    else if (e < 1024) v = (eb1a[e-512]   + eb1b[e-512]  ) * gate_scale(e-512);
    else if (e < 1536) v = (db0a[e-1024]  + db0b[e-1024] ) * gate_scale(e-1024);
    else if (e < 2048) v = (db1a[e-1536]  + db1b[e-1536] ) * gate_scale(e-1536);
    else               v = linb[e-2048];
    biases[e] = v;
  }
}

// ---------------- main fused persistent kernel ----------------
// 32 blocks (16 batch rows each) x 512 threads (8 waves).
// Wave w owns gate n-tiles {w, 8+w, 16+w, 24+w} of each layer.
// Encoder is software-pipelined: one phase computes L0(i) AND L1(i-1)
// (both depend only on h0(i-1), h1(i-2)) -> 1 barrier/step, shared h0
// operand read, two independent MFMA->activation chains for ILP.
// Weight placement (R5/R6, the capacity wall: ~290 KB reg-weights/CU max):
// W0 + W1-lo in VGPRs (144 regs/wave), W1-hi + lin in LDS.
// Activations: folded-exp2, 8 quarter-rate ops/cell (R11).
__global__ __launch_bounds__(512, 1) void lstm_main_kernel(
    const short8* __restrict__ xfrag,
    const short8* __restrict__ encW0,
    const short8* __restrict__ encW1lo, const short8* __restrict__ encW1hi,
    const short8* __restrict__ decW0,
    const short8* __restrict__ decW1lo, const short8* __restrict__ decW1hi,
    const short8* __restrict__ linT,  const float* __restrict__ biases,
    float* __restrict__ out)
{
  extern __shared__ __align__(16) char smem[];
  short8* Wlds        = (short8*)(smem + SM_W);
  short (*Abuf)[520]  = (short(*)[520])(smem + SM_ABUF);
  short (*inpA)[40]   = (short(*)[40])(smem + SM_INP);
  short8* Wlin        = (short8*)(smem + SM_LIN);

  const int tid  = threadIdx.x;
  const int w    = tid >> 6;
  const int l    = tid & 63;
  const int col  = l & 15;      // MFMA n (B,D) lane field / A m field
  const int lq   = l >> 4;
  const int bblk = blockIdx.x;

  // stage W1 hi-half (h1 part) into LDS + zero h state
  for (int i = tid; i < 8192; i += 512) Wlds[i] = encW1hi[i];
  for (int i = tid; i < 16*520; i += 512) ((short*)Abuf)[i] = 0;

  // ---- persistent weight registers (encoder first) ----
  short8 W0r[4][5];    // L0: n-tile 8i+w, kb<5  (k: 32 input + 128 h)
  short8 W1lo[4][4];   // L1 lo: n-tile 8i+w, kb<4 (k: 128 h0)
  #pragma unroll
  for (int i=0;i<4;i++){
    #pragma unroll
    for (int kb=0;kb<5;kb++) W0r[i][kb]  = encW0  [(size_t)(8*i+w)*320 + (size_t)kb*64 + l];
    #pragma unroll
    for (int kb=0;kb<4;kb++) W1lo[i][kb] = encW1lo[(size_t)(8*i+w)*256 + (size_t)kb*64 + l];
  }
  float bs0[4], bs1[4];
  #pragma unroll
  for (int i=0;i<4;i++){
    bs0[i] = biases[       (8*i+w)*16 + col];
    bs1[i] = biases[512 +  (8*i+w)*16 + col];
  }

  float c0[4] = {0.f,0.f,0.f,0.f};
  float c1[4] = {0.f,0.f,0.f,0.f};

  const short8* xf = xfrag + (size_t)bblk*T_*64 + l;
  short8 a0 = xf[0];
  __syncthreads();

  // ---------------- encoder: software-pipelined, 1 barrier/step ----------------
  // iter i (1..255): compute h0(i) [L0] and h1(i-1) [L1] in one phase.

  // ---- peel: i=0, L0 only ----
  {
    short8 hp[4];
    #pragma unroll
    for (int kb=0;kb<4;kb++) hp[kb] = *(const short8*)&Abuf[col][128 + kb*32 + lq*8];
    float4v acc0[4];
    #pragma unroll
    for (int i4=0;i4<4;i4++){
      float4v a = {bs0[i4],bs0[i4],bs0[i4],bs0[i4]};
      a = MFMA_B16(a0, W0r[i4][0], a);
      #pragma unroll
      for (int kb=0;kb<4;kb++) a = MFMA_B16(hp[kb], W0r[i4][kb+1], a);
      acc0[i4] = a;
    }
    a0 = xf[64];
    #pragma unroll
    for (int q=0;q<4;q++){
      float cc = st2(acc0[0][q], acc0[2][q]);          // f*c = 0 at t=0
      c0[q] = cc;
      Abuf[lq*4+q][0 + 16*w + col] = f2bf(st2c(acc0[3][q], cc));  // parity 0
    }
    __syncthreads();
  }

  // ---- main: i = 1..255 ----
  #pragma unroll 2
  for (int i = 1; i < T_; i++){
    const int p_h0_r = ((i-1)&1)*128;          // h0(i-1) — shared by L0 and L1
    const int p_h0_w = (i&1)*128;              // h0(i)
    const int p_h1_r = 256 + (i&1)*128;        // h1(i-2)
    const int p_h1_w = 256 + ((i-1)&1)*128;    // h1(i-1)

    short8 hp[4], h1p[4];
    #pragma unroll
    for (int kb=0;kb<4;kb++) hp[kb]  = *(const short8*)&Abuf[col][p_h0_r + kb*32 + lq*8];
    #pragma unroll
    for (int kb=0;kb<4;kb++) h1p[kb] = *(const short8*)&Abuf[col][p_h1_r + kb*32 + lq*8];

    float4v acc0[4], acc1[4];
    #pragma unroll
    for (int i4=0;i4<4;i4++){
      float4v a = {bs0[i4],bs0[i4],bs0[i4],bs0[i4]};
      a = MFMA_B16(a0, W0r[i4][0], a);
      #pragma unroll
      for (int kb=0;kb<4;kb++) a = MFMA_B16(hp[kb], W0r[i4][kb+1], a);
      acc0[i4] = a;

      float4v b = {bs1[i4],bs1[i4],bs1[i4],bs1[i4]};
      #pragma unroll
      for (int kb=0;kb<4;kb++) b = MFMA_B16(hp[kb], W1lo[i4][kb], b);
      #pragma unroll
      for (int kb=0;kb<4;kb++){
        short8 wv = Wlds[((8*i4+w)*4 + kb)*64 + l];
        b = MFMA_B16(h1p[kb], wv, b);
      }
      acc1[i4] = b;
    }
    a0 = xf[(size_t)((i+1 < T_) ? i+1 : i)*64];   // prefetch next frame

    #pragma unroll
    for (int q=0;q<4;q++){
      float cc = sigm2(acc0[1][q])*c0[q] + st2(acc0[0][q], acc0[2][q]);
      c0[q] = cc;
      Abuf[lq*4+q][p_h0_w + 16*w + col] = f2bf(st2c(acc0[3][q], cc));
    }
    #pragma unroll
    for (int q=0;q<4;q++){
      float cc = sigm2(acc1[1][q])*c1[q] + st2(acc1[0][q], acc1[2][q]);
      c1[q] = cc;
      Abuf[lq*4+q][p_h1_w + 16*w + col] = f2bf(st2c(acc1[3][q], cc));
    }
    __syncthreads();
  }

  // ---- epilogue: L1 for i-1 = 255 ----
  {
    const int p_h0_r = 128;        // h0(255), parity 1
    const int p_h1_r = 256 + 0;    // h1(254), parity 0
    const int p_h1_w = 256 + 128;  // h1(255), parity 1
    short8 hp[4], h1p[4];
    #pragma unroll
    for (int kb=0;kb<4;kb++) hp[kb]  = *(const short8*)&Abuf[col][p_h0_r + kb*32 + lq*8];
    #pragma unroll
    for (int kb=0;kb<4;kb++) h1p[kb] = *(const short8*)&Abuf[col][p_h1_r + kb*32 + lq*8];
    float4v acc1[4];
    #pragma unroll
    for (int i4=0;i4<4;i4++){
      float4v b = {bs1[i4],bs1[i4],bs1[i4],bs1[i4]};
      #pragma unroll
      for (int kb=0;kb<4;kb++) b = MFMA_B16(hp[kb], W1lo[i4][kb], b);
      #pragma unroll
      for (int kb=0;kb<4;kb++){
        short8 wv = Wlds[((8*i4+w)*4 + kb)*64 + l];
        b = MFMA_B16(h1p[kb], wv, b);
      }
      acc1[i4] = b;
    }
    #pragma unroll
    for (int q=0;q<4;q++){
      float cc = sigm2(acc1[1][q])*c1[q] + st2(acc1[0][q], acc1[2][q]);
      c1[q] = cc;
      Abuf[lq*4+q][p_h1_w + 16*w + col] = f2bf(st2c(acc1[3][q], cc));
    }
    __syncthreads();   // all encoder Wlds reads done before restage
  }

  // ---- swap weights to decoder ----
  for (int i = tid; i < 8192; i += 512) Wlds[i] = decW1hi[i];
  if (tid < 512) Wlin[tid] = linT[tid];
  #pragma unroll
  for (int i=0;i<4;i++){
    #pragma unroll
    for (int kb=0;kb<5;kb++) W0r[i][kb]  = decW0  [(size_t)(8*i+w)*320 + (size_t)kb*64 + l];
    #pragma unroll
    for (int kb=0;kb<4;kb++) W1lo[i][kb] = decW1lo[(size_t)(8*i+w)*256 + (size_t)kb*64 + l];
    bs0[i] = biases[1024 + (8*i+w)*16 + col];
    bs1[i] = biases[1536 + (8*i+w)*16 + col];
  }
  float blin = (w < 2) ? biases[2048 + w*16 + col] : 0.f;
  if (w == 0){
    *(short8*)&inpA[col][lq*8] = xf[(size_t)(T_-1)*64];   // dec input 0 = x[:,-1,:]
  }
  __syncthreads();

  // ---------------- decoder: 64 steps, 3 phases ----------------
  // enc left h0/h1 at parity 1 -> dec td reads parity (td+1)&1, writes td&1.
  #pragma unroll 2
  for (int td = 0; td < TGT; td++){
    const int h0r = ((td+1)&1) * 128;
    const int h0w = 128 - h0r;
    const int h1r = 256 + h0r;
    const int h1w = 256 + h0w;

    // ---- phase 1: layer 0 ----
    short8 a0d = *(const short8*)&inpA[col][lq*8];
    short8 ah[4];
    #pragma unroll
    for (int kb=0;kb<4;kb++) ah[kb] = *(const short8*)&Abuf[col][h0r + kb*32 + lq*8];
    float4v acc0[4];
    #pragma unroll
    for (int i=0;i<4;i++){
      float4v a = {bs0[i],bs0[i],bs0[i],bs0[i]};
      a = MFMA_B16(a0d, W0r[i][0], a);
      #pragma unroll
      for (int kb=0;kb<4;kb++) a = MFMA_B16(ah[kb], W0r[i][kb+1], a);
      acc0[i] = a;
    }
    #pragma unroll
    for (int q=0;q<4;q++){
      float cc = sigm2(acc0[1][q])*c0[q] + st2(acc0[0][q], acc0[2][q]);
      c0[q] = cc;
      Abuf[lq*4+q][h0w + 16*w + col] = f2bf(st2c(acc0[3][q], cc));
    }
    __syncthreads();

    // ---- phase 2: layer 1 ----
    short8 a1lo[4], a1hi[4];
    #pragma unroll
    for (int kb=0;kb<4;kb++) a1lo[kb] = *(const short8*)&Abuf[col][h0w + kb*32 + lq*8];
    #pragma unroll
    for (int kb=0;kb<4;kb++) a1hi[kb] = *(const short8*)&Abuf[col][h1r + kb*32 + lq*8];
    float4v acc1[4];
    #pragma unroll
    for (int i=0;i<4;i++){
      float4v a = {bs1[i],bs1[i],bs1[i],bs1[i]};
      #pragma unroll
      for (int kb=0;kb<4;kb++) a = MFMA_B16(a1lo[kb], W1lo[i][kb], a);
      #pragma unroll
      for (int kb=0;kb<4;kb++){
        short8 wv = Wlds[((8*i+w)*4 + kb)*64 + l];
        a = MFMA_B16(a1hi[kb], wv, a);
      }
      acc1[i] = a;
    }
    #pragma unroll
    for (int q=0;q<4;q++){
      float cc = sigm2(acc1[1][q])*c1[q] + st2(acc1[0][q], acc1[2][q]);
      c1[q] = cc;
      Abuf[lq*4+q][h1w + 16*w + col] = f2bf(st2c(acc1[3][q], cc));
    }
    __syncthreads();

    // ---- phase 3: projection + feedback ----
    if (w < 2){
      short8 hf[4];
      #pragma unroll
      for (int kb=0;kb<4;kb++) hf[kb] = *(const short8*)&Abuf[col][h1w + kb*32 + lq*8];
      float4v a = {blin,blin,blin,blin};
      #pragma unroll
      for (int kb=0;kb<4;kb++){
        short8 wv = Wlin[(w*4+kb)*64 + l];
        a = MFMA_B16(hf[kb], wv, a);
      }
      #pragma unroll
      for (int q=0;q<4;q++){
        float v = a[q];
        int b = bblk*16 + lq*4 + q;
        out[((size_t)b*TGT + td)*DIN + (w*16 + col)] = v;
        inpA[lq*4+q][w*16 + col] = f2bf(v);
      }
    }
    __syncthreads();
  }
}

// ---------------- host ----------------
extern "C" void kernel_launch(void* const* d_in, const int* in_sizes, int n_in,
                              void* d_out, int out_size, void* d_ws, size_t ws_size,
                              hipStream_t stream) {
  const float* x      = (const float*)d_in[0];
  const float* eWih0  = (const float*)d_in[2];
  const float* eWhh0  = (const float*)d_in[3];
  const float* eb0a   = (const float*)d_in[4];
  const float* eb0b   = (const float*)d_in[5];
  const float* eWih1  = (const float*)d_in[6];
  const float* eWhh1  = (const float*)d_in[7];
  const float* eb1a   = (const float*)d_in[8];
  const float* eb1b   = (const float*)d_in[9];
  const float* dWih0  = (const float*)d_in[10];
  const float* dWhh0  = (const float*)d_in[11];
  const float* db0a   = (const float*)d_in[12];
  const float* db0b   = (const float*)d_in[13];
  const float* dWih1  = (const float*)d_in[14];
  const float* dWhh1  = (const float*)d_in[15];
  const float* db1a   = (const float*)d_in[16];
  const float* db1b   = (const float*)d_in[17];
  const float* linW   = (const float*)d_in[18];
  const float* linb   = (const float*)d_in[19];

  char* ws = (char*)d_ws;
  short8* xfrag   = (short8*)(ws + OFF_XFRAG);
  short8* encW0   = (short8*)(ws + OFF_EW0);
  short8* encW1lo = (short8*)(ws + OFF_EW1LO);
  short8* encW1hi = (short8*)(ws + OFF_EW1HI);
  short8* decW0   = (short8*)(ws + OFF_DW0);
  short8* decW1lo = (short8*)(ws + OFF_DW1LO);
  short8* decW1hi = (short8*)(ws + OFF_DW1HI);
  short8* linT    = (short8*)(ws + OFF_LIN);
  float*  biases  = (float*)(ws + OFF_BIAS);

  // allow >64 KB dynamic LDS (host-side attribute, graph-capture safe)
  hipFuncSetAttribute((const void*)lstm_main_kernel,
                      hipFuncAttributeMaxDynamicSharedMemorySize, SM_TOTAL);

  prep_x_kernel<<<2048, 256, 0, stream>>>(x, xfrag);
  prep_w_kernel<<<219, 256, 0, stream>>>(
      eWih0,eWhh0,eWih1,eWhh1,dWih0,dWhh0,dWih1,dWhh1,linW,
      eb0a,eb0b,eb1a,eb1b,db0a,db0b,db1a,db1b,linb,
      encW0,encW1lo,encW1hi,decW0,decW1lo,decW1hi,linT,biases);
  lstm_main_kernel<<<32, 512, SM_TOTAL, stream>>>(
      xfrag, encW0, encW1lo, encW1hi, decW0, decW1lo, decW1hi,
      linT, biases, (float*)d_out);
}